// Round 8
// baseline (1883.647 us; speedup 1.0000x reference)
//
#include <hip/hip_runtime.h>

#define B_ 16
#define N_ 4096
#define M_ 1024
#define S_ 32
#define IN_ 64
#define C0IN 67
#define C0 64
#define C1 64
#define C2 128
#define NTOT (B_*M_*S_)
#define R2 0.04f
#define CAP 1024
#define NBUCK 16
#define BQ_G 32

#define FPS_T 256
#define FPS_PTS 16

// 64-bit DPP max (packed key).
#define DPP_U64_MAX(k, ctrl) { \
    unsigned int _lo = (unsigned int)(k), _hi = (unsigned int)((k) >> 32); \
    unsigned int _olo = (unsigned int)__builtin_amdgcn_update_dpp((int)_lo, (int)_lo, ctrl, 0xF, 0xF, false); \
    unsigned int _ohi = (unsigned int)__builtin_amdgcn_update_dpp((int)_hi, (int)_hi, ctrl, 0xF, 0xF, false); \
    unsigned long long _o = ((unsigned long long)_ohi << 32) | _olo; \
    if (_o > (k)) (k) = _o; }

// ---------------- FPS ---------------- (unchanged, proven: 662 us; dist phase
// is CU-issue-bound at 4 waves -- more waves proven slower in rounds 1/4)
__global__ __launch_bounds__(FPS_T, 1) void fps_kernel(const float* __restrict__ xyz,
                                                       int* __restrict__ fps_idx,
                                                       float* __restrict__ out_xyz) {
#pragma clang fp contract(off)
    __shared__ float4 pxyz[N_];
    __shared__ int    sel[M_];
    __shared__ __align__(16) unsigned long long slotk[2][4];
    int b = blockIdx.x, t = threadIdx.x;
    const float* xb = xyz + (size_t)b * N_ * 3;
    float lx[FPS_PTS], ly[FPS_PTS], lz[FPS_PTS], dl[FPS_PTS];
#pragma unroll
    for (int j = 0; j < FPS_PTS; j++) {
        int i = (j << 8) + t;
        float x = xb[3*i], y = xb[3*i+1], z = xb[3*i+2];
        lx[j] = x; ly[j] = y; lz[j] = z;
        dl[j] = __builtin_inff();
        pxyz[i] = make_float4(x, y, z, 0.f);
    }
    __syncthreads();
    int wid = t >> 6, lane = t & 63;
    int cur = 0;
    float4 cc = pxyz[0];
    for (int k = 0; k < M_; k++) {
        float cx = cc.x, cy = cc.y, cz = cc.z;
        if (t == 0) sel[k] = cur;
#pragma unroll
        for (int j = 0; j < FPS_PTS; j++)
            asm volatile("" : "+v"(lx[j]), "+v"(ly[j]), "+v"(lz[j]));
        float bv = -1.0f; int bi = 0x7fffffff;
#pragma unroll
        for (int j = 0; j < FPS_PTS; j++) {
            float dx = lx[j] - cx, dy = ly[j] - cy, dz = lz[j] - cz;
            float t0 = dx*dx, t1 = dy*dy, t2 = dz*dz;
            float d = (t0 + t1) + t2;
            float od = dl[j];
            float nd = d < od ? d : od;
            dl[j] = nd;
            if (nd > bv) { bv = nd; bi = (j << 8) + t; }
        }
        unsigned long long key = ((unsigned long long)__float_as_uint(bv) << 32)
                               | (unsigned int)(~bi);
        DPP_U64_MAX(key, 0x111);
        DPP_U64_MAX(key, 0x112);
        DPP_U64_MAX(key, 0x114);
        DPP_U64_MAX(key, 0x118);
        DPP_U64_MAX(key, 0x142);
        DPP_U64_MAX(key, 0x143);
        int p = k & 1;
        if (lane == 63) slotk[p][wid] = key;
        __syncthreads();
        ulonglong2 s01 = *(const ulonglong2*)&slotk[p][0];
        ulonglong2 s23 = *(const ulonglong2*)&slotk[p][2];
        unsigned long long kk = s01.x;
        if (s01.y > kk) kk = s01.y;
        if (s23.x > kk) kk = s23.x;
        if (s23.y > kk) kk = s23.y;
        cur = (int)(~(unsigned int)kk);
        cc = pxyz[cur];
    }
    __syncthreads();
    for (int i = t; i < M_; i += FPS_T) {
        int ix = sel[i];
        float4 q = pxyz[ix];
        fps_idx[b*M_ + i] = ix;
        out_xyz[(b*M_ + i)*3 + 0] = q.x;
        out_xyz[(b*M_ + i)*3 + 1] = q.y;
        out_xyz[(b*M_ + i)*3 + 2] = q.z;
    }
}

// ---------------- Ball query (grouped, proven round 7) ----------------
__global__ __launch_bounds__(256) void ballq_kernel(const float* __restrict__ xyz,
                                                    const int* __restrict__ fps_idx,
                                                    int* __restrict__ ball_idx) {
#pragma clang fp contract(off)
    __shared__ float4 pts[N_];
    __shared__ float cd[CAP];
    __shared__ int   ci[CAP];
    __shared__ int   cnt;
    __shared__ float rv[4];
    __shared__ int   ri[4];
    __shared__ int   slots[33];
    int blk = blockIdx.x;
    int b = blk >> 5;
    int g = blk & 31;
    int t = threadIdx.x;
    const float* xb = xyz + (size_t)b * N_ * 3;
    for (int i = t; i < N_; i += 256)
        pts[i] = make_float4(xb[i*3+0], xb[i*3+1], xb[i*3+2], 0.f);
    __syncthreads();
    for (int mm = 0; mm < BQ_G; mm++) {
        int m = (g << 5) + mm;
        if (t == 0) cnt = 0;
        __syncthreads();
        float4 c4 = pts[fps_idx[b*M_ + m]];
        float cx = c4.x, cy = c4.y, cz = c4.z;
        float bv = 3.4e38f; int bi = 0x7fffffff;
        for (int i = t; i < N_; i += 256) {
            float4 p = pts[i];
            float dx = p.x - cx, dy = p.y - cy, dz = p.z - cz;
            float t0 = dx*dx, t1 = dy*dy, t2 = dz*dz;
            float d = (t0 + t1) + t2;
            if (d < bv || (d == bv && i < bi)) { bv = d; bi = i; }
            if (d <= R2) {
                int pp = atomicAdd(&cnt, 1);
                if (pp < CAP) { cd[pp] = d; ci[pp] = i; }
            }
        }
        for (int off = 32; off >= 1; off >>= 1) {
            float ov = __shfl_xor(bv, off, 64);
            int   oi = __shfl_xor(bi, off, 64);
            if (ov < bv || (ov == bv && oi < bi)) { bv = ov; bi = oi; }
        }
        int w = t >> 6;
        if ((t & 63) == 0) { rv[w] = bv; ri[w] = bi; }
        __syncthreads();
        int n = cnt < CAP ? cnt : CAP;
        for (int j = t; j < n; j += 256) {
            float dj = cd[j]; int ij = ci[j];
            int rank = 0;
            for (int k = 0; k < n; k++) {
                float dk = cd[k]; int ik = ci[k];
                rank += (dk < dj) || (dk == dj && ik < ij);
            }
            if (rank < S_) slots[rank] = ij;
        }
        if (t == 0) {
            float v = rv[0]; int ix = ri[0];
            for (int j = 1; j < 4; j++)
                if (rv[j] < v || (rv[j] == v && ri[j] < ix)) { v = rv[j]; ix = ri[j]; }
            slots[32] = ix;
        }
        __syncthreads();
        if (t < S_) {
            int nearest = (n > 0) ? slots[0] : slots[32];
            int ix = (t < n) ? slots[t] : nearest;
            ball_idx[(size_t)(b*M_ + m)*S_ + t] = ix;
        }
    }
}

// ============ Staged pipeline, 2-outputs-per-thread inner loops ============
// Each ds_read_b128 of activations feeds 8 FMAs (4 ch x 2 weight rows) --
// halves the LDS-pipe traffic that bounds these kernels. Per-(d,s) value is
// bit-exact (same c-ascending order). Per-channel stats via [ch][grp] LDS
// partials (stride 9/5: coprime with 32 banks -> conflict-free).

// S1: gather + L0 -> z0, stats0. thread = (dp = t&31 -> d{2dp,2dp+1}, sg = t>>5, s = 4sg+q)
__global__ __launch_bounds__(256) void mlpS1_kernel(
    const float* __restrict__ xyz, const float* __restrict__ feat,
    const int* __restrict__ fps_idx, const int* __restrict__ ball_idx,
    const float* __restrict__ w0, const float* __restrict__ b0,
    float* __restrict__ zbuf, float* __restrict__ stats) {
    __shared__ __align__(16) float xs[S_][68];   // col 67 = 0 pad
    __shared__ float rsum[64][9], rsq[64][9];
    __shared__ int idxs[S_];
    int blk = blockIdx.x, b = blk >> 10, m = blk & (M_ - 1), t = threadIdx.x;
    const float* xb = xyz + (size_t)b * N_ * 3;
    int cidx = fps_idx[b*M_ + m];
    float cx = xb[cidx*3+0], cy = xb[cidx*3+1], cz = xb[cidx*3+2];
    if (t < S_) idxs[t] = ball_idx[(size_t)blk * S_ + t];
    __syncthreads();
    for (int i = t; i < S_*68; i += 256) {
        int s = i / 68, c = i - s * 68;
        int p = idxs[s];
        float v;
        if (c == 0)       v = xb[p*3+0] - cx;
        else if (c == 1)  v = xb[p*3+1] - cy;
        else if (c == 2)  v = xb[p*3+2] - cz;
        else if (c == 67) v = 0.f;
        else              v = feat[((size_t)b*N_ + p)*IN_ + (c - 3)];
        xs[s][c] = v;
    }
    __syncthreads();
    int dp = t & 31, sg = t >> 5;
    int d0 = dp * 2;
    const float* wa = w0 + (size_t)d0 * C0IN;
    const float* wb = wa + C0IN;
    float acc[2][4];
    {
        float bi0 = b0[d0], bi1 = b0[d0+1];
#pragma unroll
        for (int q = 0; q < 4; q++) { acc[0][q] = bi0; acc[1][q] = bi1; }
    }
    {   // half A: c = 0..31
        float w0r[32], w1r[32];
#pragma unroll
        for (int c = 0; c < 32; c++) { w0r[c] = wa[c]; w1r[c] = wb[c]; }
#pragma unroll
        for (int q = 0; q < 4; q++) {
            const float4* x4 = (const float4*)&xs[sg*4 + q][0];
#pragma unroll
            for (int c4 = 0; c4 < 8; c4++) {
                float4 v = x4[c4];
                acc[0][q] += v.x * w0r[4*c4+0]; acc[1][q] += v.x * w1r[4*c4+0];
                acc[0][q] += v.y * w0r[4*c4+1]; acc[1][q] += v.y * w1r[4*c4+1];
                acc[0][q] += v.z * w0r[4*c4+2]; acc[1][q] += v.z * w1r[4*c4+2];
                acc[0][q] += v.w * w0r[4*c4+3]; acc[1][q] += v.w * w1r[4*c4+3];
            }
        }
    }
    {   // half B: c = 32..67 (35 real + 0 pad)
        float w0r[36], w1r[36];
#pragma unroll
        for (int c = 0; c < 35; c++) { w0r[c] = wa[32+c]; w1r[c] = wb[32+c]; }
        w0r[35] = 0.f; w1r[35] = 0.f;
#pragma unroll
        for (int q = 0; q < 4; q++) {
            const float4* x4 = ((const float4*)&xs[sg*4 + q][0]) + 8;
#pragma unroll
            for (int c4 = 0; c4 < 9; c4++) {
                float4 v = x4[c4];
                acc[0][q] += v.x * w0r[4*c4+0]; acc[1][q] += v.x * w1r[4*c4+0];
                acc[0][q] += v.y * w0r[4*c4+1]; acc[1][q] += v.y * w1r[4*c4+1];
                acc[0][q] += v.z * w0r[4*c4+2]; acc[1][q] += v.z * w1r[4*c4+2];
                acc[0][q] += v.w * w0r[4*c4+3]; acc[1][q] += v.w * w1r[4*c4+3];
            }
        }
    }
    float ls0 = 0.f, lq0 = 0.f, ls1 = 0.f, lq1 = 0.f;
    float* zt = zbuf + (size_t)blk * 2048;
#pragma unroll
    for (int q = 0; q < 4; q++) {
        int s = sg*4 + q;
        float a0 = acc[0][q], a1 = acc[1][q];
        *(float2*)&zt[s*64 + d0] = make_float2(a0, a1);
        ls0 += a0; lq0 += a0*a0; ls1 += a1; lq1 += a1*a1;
    }
    rsum[d0][sg] = ls0; rsq[d0][sg] = lq0;
    rsum[d0+1][sg] = ls1; rsq[d0+1][sg] = lq1;
    __syncthreads();
    if (t < 64) {
        float s = 0.f, s2 = 0.f;
#pragma unroll
        for (int j = 0; j < 8; j++) { s += rsum[t][j]; s2 += rsq[t][j]; }
        float* sb = stats + (size_t)(blk & (NBUCK-1)) * 512;
        atomicAdd(&sb[t], s);
        atomicAdd(&sb[64 + t], s2);
    }
}

// S2: z0 -> BN0+relu -> L1 -> z1 (in-place), stats1
__global__ __launch_bounds__(256) void mlpS2_kernel(
    float* __restrict__ zbuf,
    const float* __restrict__ w1, const float* __restrict__ b1,
    const float* __restrict__ g0, const float* __restrict__ be0,
    float* __restrict__ stats) {
    __shared__ __align__(16) float y0s[S_][C0];
    __shared__ float rsum[64][9], rsq[64][9];
    __shared__ float lc[128];
    int blk = blockIdx.x, t = threadIdx.x;
    const float inv_n = 1.0f / (float)NTOT;
    if (t < 64) {
        float s = 0.f, s2 = 0.f;
        for (int j = 0; j < NBUCK; j++) { s += stats[j*512 + t]; s2 += stats[j*512 + 64 + t]; }
        float mean = s * inv_n, var = s2 * inv_n - mean * mean;
        float a = g0[t] * (1.0f / sqrtf(var + 1e-5f));
        lc[t] = a; lc[64 + t] = be0[t] - mean * a;
    }
    int dc = t & 63;
    float* zt = zbuf + (size_t)blk * 2048;
    float zv[8];
#pragma unroll
    for (int j = 0; j < 8; j++) zv[j] = zt[t + 256*j];
    __syncthreads();   // lc ready
    float a0c = lc[dc], c0c = lc[64 + dc];
#pragma unroll
    for (int j = 0; j < 8; j++) {
        float v = zv[j] * a0c + c0c;
        y0s[(t >> 6) + 4*j][dc] = v > 0.f ? v : 0.f;
    }
    __syncthreads();   // y0s ready
    int dp = t & 31, sg = t >> 5;
    int d0 = dp * 2;
    const float* wa = w1 + (size_t)d0 * C0;
    const float* wb = wa + C0;
    float acc[2][4];
    {
        float bi0 = b1[d0], bi1 = b1[d0+1];
#pragma unroll
        for (int q = 0; q < 4; q++) { acc[0][q] = bi0; acc[1][q] = bi1; }
    }
    {   // half A
        float w0r[32], w1r[32];
#pragma unroll
        for (int c = 0; c < 32; c++) { w0r[c] = wa[c]; w1r[c] = wb[c]; }
#pragma unroll
        for (int q = 0; q < 4; q++) {
            const float4* x4 = (const float4*)&y0s[sg*4 + q][0];
#pragma unroll
            for (int c4 = 0; c4 < 8; c4++) {
                float4 v = x4[c4];
                acc[0][q] += v.x * w0r[4*c4+0]; acc[1][q] += v.x * w1r[4*c4+0];
                acc[0][q] += v.y * w0r[4*c4+1]; acc[1][q] += v.y * w1r[4*c4+1];
                acc[0][q] += v.z * w0r[4*c4+2]; acc[1][q] += v.z * w1r[4*c4+2];
                acc[0][q] += v.w * w0r[4*c4+3]; acc[1][q] += v.w * w1r[4*c4+3];
            }
        }
    }
    {   // half B
        float w0r[32], w1r[32];
#pragma unroll
        for (int c = 0; c < 32; c++) { w0r[c] = wa[32+c]; w1r[c] = wb[32+c]; }
#pragma unroll
        for (int q = 0; q < 4; q++) {
            const float4* x4 = ((const float4*)&y0s[sg*4 + q][0]) + 8;
#pragma unroll
            for (int c4 = 0; c4 < 8; c4++) {
                float4 v = x4[c4];
                acc[0][q] += v.x * w0r[4*c4+0]; acc[1][q] += v.x * w1r[4*c4+0];
                acc[0][q] += v.y * w0r[4*c4+1]; acc[1][q] += v.y * w1r[4*c4+1];
                acc[0][q] += v.z * w0r[4*c4+2]; acc[1][q] += v.z * w1r[4*c4+2];
                acc[0][q] += v.w * w0r[4*c4+3]; acc[1][q] += v.w * w1r[4*c4+3];
            }
        }
    }
    float ls0 = 0.f, lq0 = 0.f, ls1 = 0.f, lq1 = 0.f;
#pragma unroll
    for (int q = 0; q < 4; q++) {
        int s = sg*4 + q;
        float a0 = acc[0][q], a1 = acc[1][q];
        *(float2*)&zt[s*64 + d0] = make_float2(a0, a1);   // all zt reads done pre-barrier
        ls0 += a0; lq0 += a0*a0; ls1 += a1; lq1 += a1*a1;
    }
    rsum[d0][sg] = ls0; rsq[d0][sg] = lq0;
    rsum[d0+1][sg] = ls1; rsq[d0+1][sg] = lq1;
    __syncthreads();
    if (t < 64) {
        float s = 0.f, s2 = 0.f;
#pragma unroll
        for (int j = 0; j < 8; j++) { s += rsum[t][j]; s2 += rsq[t][j]; }
        float* sb = stats + (size_t)(blk & (NBUCK-1)) * 512;
        atomicAdd(&sb[128 + t], s);
        atomicAdd(&sb[192 + t], s2);
    }
}

// S3: z1 -> BN1+relu -> L2 -> stats2 (+ optional z2 store).
// thread = (dp = t&63 -> d{2dp,2dp+1}, sg = t>>6, s = 8sg+q)
template<int STOREZ>
__global__ __launch_bounds__(256) void mlpS3_kernel(
    const float* __restrict__ zbuf,
    const float* __restrict__ w2, const float* __restrict__ b2,
    const float* __restrict__ g1, const float* __restrict__ be1,
    float* __restrict__ z2buf, float* __restrict__ stats) {
    __shared__ __align__(16) float y1s[S_][C1];
    __shared__ float rsum[128][5], rsq[128][5];
    __shared__ float lc[128];
    int blk = blockIdx.x, t = threadIdx.x;
    const float inv_n = 1.0f / (float)NTOT;
    if (t < 64) {
        float s = 0.f, s2 = 0.f;
        for (int j = 0; j < NBUCK; j++) { s += stats[j*512 + 128 + t]; s2 += stats[j*512 + 192 + t]; }
        float mean = s * inv_n, var = s2 * inv_n - mean * mean;
        float a = g1[t] * (1.0f / sqrtf(var + 1e-5f));
        lc[t] = a; lc[64 + t] = be1[t] - mean * a;
    }
    int dc = t & 63;
    const float* zt = zbuf + (size_t)blk * 2048;
    float zv[8];
#pragma unroll
    for (int j = 0; j < 8; j++) zv[j] = zt[t + 256*j];
    __syncthreads();
    float a1c = lc[dc], c1c = lc[64 + dc];
#pragma unroll
    for (int j = 0; j < 8; j++) {
        float v = zv[j] * a1c + c1c;
        y1s[(t >> 6) + 4*j][dc] = v > 0.f ? v : 0.f;
    }
    __syncthreads();
    int dp = t & 63, sg = t >> 6;
    int d0 = dp * 2;
    const float* wa = w2 + (size_t)d0 * C1;
    const float* wb = wa + C1;
    float acc[2][8];
    {
        float bi0 = b2[d0], bi1 = b2[d0+1];
#pragma unroll
        for (int q = 0; q < 8; q++) { acc[0][q] = bi0; acc[1][q] = bi1; }
    }
    {   // half A
        float w0r[32], w1r[32];
#pragma unroll
        for (int c = 0; c < 32; c++) { w0r[c] = wa[c]; w1r[c] = wb[c]; }
#pragma unroll
        for (int q = 0; q < 8; q++) {
            const float4* x4 = (const float4*)&y1s[sg*8 + q][0];
#pragma unroll
            for (int c4 = 0; c4 < 8; c4++) {
                float4 v = x4[c4];
                acc[0][q] += v.x * w0r[4*c4+0]; acc[1][q] += v.x * w1r[4*c4+0];
                acc[0][q] += v.y * w0r[4*c4+1]; acc[1][q] += v.y * w1r[4*c4+1];
                acc[0][q] += v.z * w0r[4*c4+2]; acc[1][q] += v.z * w1r[4*c4+2];
                acc[0][q] += v.w * w0r[4*c4+3]; acc[1][q] += v.w * w1r[4*c4+3];
            }
        }
    }
    {   // half B
        float w0r[32], w1r[32];
#pragma unroll
        for (int c = 0; c < 32; c++) { w0r[c] = wa[32+c]; w1r[c] = wb[32+c]; }
#pragma unroll
        for (int q = 0; q < 8; q++) {
            const float4* x4 = ((const float4*)&y1s[sg*8 + q][0]) + 8;
#pragma unroll
            for (int c4 = 0; c4 < 8; c4++) {
                float4 v = x4[c4];
                acc[0][q] += v.x * w0r[4*c4+0]; acc[1][q] += v.x * w1r[4*c4+0];
                acc[0][q] += v.y * w0r[4*c4+1]; acc[1][q] += v.y * w1r[4*c4+1];
                acc[0][q] += v.z * w0r[4*c4+2]; acc[1][q] += v.z * w1r[4*c4+2];
                acc[0][q] += v.w * w0r[4*c4+3]; acc[1][q] += v.w * w1r[4*c4+3];
            }
        }
    }
    float ls0 = 0.f, lq0 = 0.f, ls1 = 0.f, lq1 = 0.f;
    float* z2t = z2buf + (size_t)blk * 4096;
#pragma unroll
    for (int q = 0; q < 8; q++) {
        float a0 = acc[0][q], a1 = acc[1][q];
        if (STOREZ) {
            int s = sg*8 + q;
            *(float2*)&z2t[s*128 + d0] = make_float2(a0, a1);
        }
        ls0 += a0; lq0 += a0*a0; ls1 += a1; lq1 += a1*a1;
    }
    rsum[d0][sg] = ls0; rsq[d0][sg] = lq0;
    rsum[d0+1][sg] = ls1; rsq[d0+1][sg] = lq1;
    __syncthreads();
    if (t < 128) {
        float s = 0.f, s2 = 0.f;
#pragma unroll
        for (int j = 0; j < 4; j++) { s += rsum[t][j]; s2 += rsq[t][j]; }
        float* sb = stats + (size_t)(blk & (NBUCK-1)) * 512;
        atomicAdd(&sb[256 + t], s);
        atomicAdd(&sb[384 + t], s2);
    }
}

// S4z: z2 -> BN2+relu -> max -> out (pure streaming; used when z2 staged)
__global__ __launch_bounds__(256) void mlpS4z_kernel(
    const float* __restrict__ z2buf,
    const float* __restrict__ g2, const float* __restrict__ be2,
    const float* __restrict__ stats, float* __restrict__ out_feat) {
    __shared__ float red[256];
    __shared__ float lc[256];
    int blk = blockIdx.x, t = threadIdx.x;
    const float inv_n = 1.0f / (float)NTOT;
    if (t < 128) {
        float s = 0.f, s2 = 0.f;
        for (int j = 0; j < NBUCK; j++) { s += stats[j*512 + 256 + t]; s2 += stats[j*512 + 384 + t]; }
        float mean = s * inv_n, var = s2 * inv_n - mean * mean;
        float a = g2[t] * (1.0f / sqrtf(var + 1e-5f));
        lc[t] = a; lc[128 + t] = be2[t] - mean * a;
    }
    const float* z2t = z2buf + (size_t)blk * 4096;
    float zv[16];
#pragma unroll
    for (int j = 0; j < 16; j++) zv[j] = z2t[t + 256*j];
    __syncthreads();
    int d = t & 127;
    float a2 = lc[d], c2 = lc[128 + d];
    float lmax = -3.4e38f;
#pragma unroll
    for (int j = 0; j < 16; j++) {
        float v = zv[j] * a2 + c2;
        v = v > 0.f ? v : 0.f;
        lmax = v > lmax ? v : lmax;
    }
    red[t] = lmax;
    __syncthreads();
    if (t < 128) {
        float v = red[t] > red[t+128] ? red[t] : red[t+128];
        out_feat[(size_t)blk * C2 + t] = v;
    }
}

// S4r: recompute variant (ws too small for z2): z1 -> BN1+relu -> L2 -> BN2+relu -> max
__global__ __launch_bounds__(256) void mlpS4r_kernel(
    const float* __restrict__ zbuf,
    const float* __restrict__ w2, const float* __restrict__ b2,
    const float* __restrict__ g1, const float* __restrict__ be1,
    const float* __restrict__ g2, const float* __restrict__ be2,
    const float* __restrict__ stats, float* __restrict__ out_feat) {
    __shared__ __align__(16) float y1s[S_][C1];
    __shared__ float rmax[128][5];
    __shared__ float lc[384];   // [a1 64|c1 64|a2 128|c2 128]
    int blk = blockIdx.x, t = threadIdx.x;
    const float inv_n = 1.0f / (float)NTOT;
    if (t < 64) {
        float s = 0.f, s2 = 0.f;
        for (int j = 0; j < NBUCK; j++) { s += stats[j*512 + 128 + t]; s2 += stats[j*512 + 192 + t]; }
        float mean = s * inv_n, var = s2 * inv_n - mean * mean;
        float a = g1[t] * (1.0f / sqrtf(var + 1e-5f));
        lc[t] = a; lc[64 + t] = be1[t] - mean * a;
    }
    if (t < 128) {
        float s = 0.f, s2 = 0.f;
        for (int j = 0; j < NBUCK; j++) { s += stats[j*512 + 256 + t]; s2 += stats[j*512 + 384 + t]; }
        float mean = s * inv_n, var = s2 * inv_n - mean * mean;
        float a = g2[t] * (1.0f / sqrtf(var + 1e-5f));
        lc[128 + t] = a; lc[256 + t] = be2[t] - mean * a;
    }
    int dc = t & 63;
    const float* zt = zbuf + (size_t)blk * 2048;
    float zv[8];
#pragma unroll
    for (int j = 0; j < 8; j++) zv[j] = zt[t + 256*j];
    __syncthreads();
    float a1c = lc[dc], c1c = lc[64 + dc];
#pragma unroll
    for (int j = 0; j < 8; j++) {
        float v = zv[j] * a1c + c1c;
        y1s[(t >> 6) + 4*j][dc] = v > 0.f ? v : 0.f;
    }
    __syncthreads();
    int dp = t & 63, sg = t >> 6;
    int d0 = dp * 2;
    const float* wa = w2 + (size_t)d0 * C1;
    const float* wb = wa + C1;
    float acc[2][8];
    {
        float bi0 = b2[d0], bi1 = b2[d0+1];
#pragma unroll
        for (int q = 0; q < 8; q++) { acc[0][q] = bi0; acc[1][q] = bi1; }
    }
    {   // half A
        float w0r[32], w1r[32];
#pragma unroll
        for (int c = 0; c < 32; c++) { w0r[c] = wa[c]; w1r[c] = wb[c]; }
#pragma unroll
        for (int q = 0; q < 8; q++) {
            const float4* x4 = (const float4*)&y1s[sg*8 + q][0];
#pragma unroll
            for (int c4 = 0; c4 < 8; c4++) {
                float4 v = x4[c4];
                acc[0][q] += v.x * w0r[4*c4+0]; acc[1][q] += v.x * w1r[4*c4+0];
                acc[0][q] += v.y * w0r[4*c4+1]; acc[1][q] += v.y * w1r[4*c4+1];
                acc[0][q] += v.z * w0r[4*c4+2]; acc[1][q] += v.z * w1r[4*c4+2];
                acc[0][q] += v.w * w0r[4*c4+3]; acc[1][q] += v.w * w1r[4*c4+3];
            }
        }
    }
    {   // half B
        float w0r[32], w1r[32];
#pragma unroll
        for (int c = 0; c < 32; c++) { w0r[c] = wa[32+c]; w1r[c] = wb[32+c]; }
#pragma unroll
        for (int q = 0; q < 8; q++) {
            const float4* x4 = ((const float4*)&y1s[sg*8 + q][0]) + 8;
#pragma unroll
            for (int c4 = 0; c4 < 8; c4++) {
                float4 v = x4[c4];
                acc[0][q] += v.x * w0r[4*c4+0]; acc[1][q] += v.x * w1r[4*c4+0];
                acc[0][q] += v.y * w0r[4*c4+1]; acc[1][q] += v.y * w1r[4*c4+1];
                acc[0][q] += v.z * w0r[4*c4+2]; acc[1][q] += v.z * w1r[4*c4+2];
                acc[0][q] += v.w * w0r[4*c4+3]; acc[1][q] += v.w * w1r[4*c4+3];
            }
        }
    }
    float a20 = lc[128 + d0], c20 = lc[256 + d0];
    float a21 = lc[128 + d0 + 1], c21 = lc[256 + d0 + 1];
    float lm0 = -3.4e38f, lm1 = -3.4e38f;
#pragma unroll
    for (int q = 0; q < 8; q++) {
        float v0 = acc[0][q] * a20 + c20; v0 = v0 > 0.f ? v0 : 0.f;
        float v1 = acc[1][q] * a21 + c21; v1 = v1 > 0.f ? v1 : 0.f;
        lm0 = v0 > lm0 ? v0 : lm0;
        lm1 = v1 > lm1 ? v1 : lm1;
    }
    rmax[d0][sg] = lm0; rmax[d0+1][sg] = lm1;
    __syncthreads();
    if (t < 128) {
        float v = rmax[t][0];
#pragma unroll
        for (int j = 1; j < 4; j++) v = rmax[t][j] > v ? rmax[t][j] : v;
        out_feat[(size_t)blk * C2 + t] = v;
    }
}

extern "C" void kernel_launch(void* const* d_in, const int* in_sizes, int n_in,
                              void* d_out, int out_size, void* d_ws, size_t ws_size,
                              hipStream_t stream) {
    const float* xyz  = (const float*)d_in[0];
    const float* feat = (const float*)d_in[1];
    const float* w0 = (const float*)d_in[2];  const float* b0 = (const float*)d_in[3];
    const float* g0 = (const float*)d_in[4];  const float* be0 = (const float*)d_in[5];
    const float* w1 = (const float*)d_in[6];  const float* b1 = (const float*)d_in[7];
    const float* g1 = (const float*)d_in[8];  const float* be1 = (const float*)d_in[9];
    const float* w2 = (const float*)d_in[10]; const float* b2 = (const float*)d_in[11];
    const float* g2 = (const float*)d_in[12]; const float* be2 = (const float*)d_in[13];
    float* out_xyz  = (float*)d_out;
    float* out_feat = out_xyz + B_*M_*3;

    int* fps_i  = (int*)d_ws;                                   // 64 KB
    int* ball_i = (int*)((char*)d_ws + 65536);                  // 2 MB
    float* stats = (float*)((char*)d_ws + 65536 + 2097152);     // 32 KB
    size_t zoff = 65536 + 2097152 + (size_t)NBUCK*512*4;
    float* zbuf = (float*)((char*)d_ws + zoff);                 // 128 MB
    float* z2buf = zbuf + (size_t)B_*M_ * 2048;                 // 256 MB
    size_t need2 = zoff + (size_t)B_*M_ * 2048 * 4 + (size_t)B_*M_ * 4096 * 4;
    bool stage_z2 = ws_size >= need2;

    hipMemsetAsync(stats, 0, NBUCK*512*sizeof(float), stream);
    fps_kernel<<<B_, FPS_T, 0, stream>>>(xyz, fps_i, out_xyz);
    ballq_kernel<<<B_ * (M_/BQ_G), 256, 0, stream>>>(xyz, fps_i, ball_i);
    mlpS1_kernel<<<B_*M_, 256, 0, stream>>>(xyz, feat, fps_i, ball_i, w0, b0, zbuf, stats);
    mlpS2_kernel<<<B_*M_, 256, 0, stream>>>(zbuf, w1, b1, g0, be0, stats);
    if (stage_z2) {
        mlpS3_kernel<1><<<B_*M_, 256, 0, stream>>>(zbuf, w2, b2, g1, be1, z2buf, stats);
        mlpS4z_kernel<<<B_*M_, 256, 0, stream>>>(z2buf, g2, be2, stats, out_feat);
    } else {
        mlpS3_kernel<0><<<B_*M_, 256, 0, stream>>>(zbuf, w2, b2, g1, be1, z2buf, stats);
        mlpS4r_kernel<<<B_*M_, 256, 0, stream>>>(zbuf, w2, b2, g1, be1, g2, be2, stats, out_feat);
    }
}

// Round 9
// 1623.900 us; speedup vs baseline: 1.1600x; 1.1600x over previous
//
#include <hip/hip_runtime.h>

#define B_ 16
#define N_ 4096
#define M_ 1024
#define S_ 32
#define IN_ 64
#define C0IN 67
#define C0 64
#define C1 64
#define C2 128
#define NTOT (B_*M_*S_)
#define R2 0.04f
#define CAP 1024
#define NBUCK 16
#define BQ_G 32
#define MCEN 8    // centers per MLP block: weight regs amortized 8x

#define FPS_T 256
#define FPS_PTS 16

// 64-bit DPP max (packed key).
#define DPP_U64_MAX(k, ctrl) { \
    unsigned int _lo = (unsigned int)(k), _hi = (unsigned int)((k) >> 32); \
    unsigned int _olo = (unsigned int)__builtin_amdgcn_update_dpp((int)_lo, (int)_lo, ctrl, 0xF, 0xF, false); \
    unsigned int _ohi = (unsigned int)__builtin_amdgcn_update_dpp((int)_hi, (int)_hi, ctrl, 0xF, 0xF, false); \
    unsigned long long _o = ((unsigned long long)_ohi << 32) | _olo; \
    if (_o > (k)) (k) = _o; }

// ---------------- FPS ---------------- (frozen, proven 662 us; dist phase is
// CU-issue-bound: 4096 pts / 128 lanes-per-cy regardless of wave count)
__global__ __launch_bounds__(FPS_T, 1) void fps_kernel(const float* __restrict__ xyz,
                                                       int* __restrict__ fps_idx,
                                                       float* __restrict__ out_xyz) {
#pragma clang fp contract(off)
    __shared__ float4 pxyz[N_];
    __shared__ int    sel[M_];
    __shared__ __align__(16) unsigned long long slotk[2][4];
    int b = blockIdx.x, t = threadIdx.x;
    const float* xb = xyz + (size_t)b * N_ * 3;
    float lx[FPS_PTS], ly[FPS_PTS], lz[FPS_PTS], dl[FPS_PTS];
#pragma unroll
    for (int j = 0; j < FPS_PTS; j++) {
        int i = (j << 8) + t;
        float x = xb[3*i], y = xb[3*i+1], z = xb[3*i+2];
        lx[j] = x; ly[j] = y; lz[j] = z;
        dl[j] = __builtin_inff();
        pxyz[i] = make_float4(x, y, z, 0.f);
    }
    __syncthreads();
    int wid = t >> 6, lane = t & 63;
    int cur = 0;
    float4 cc = pxyz[0];
    for (int k = 0; k < M_; k++) {
        float cx = cc.x, cy = cc.y, cz = cc.z;
        if (t == 0) sel[k] = cur;
#pragma unroll
        for (int j = 0; j < FPS_PTS; j++)
            asm volatile("" : "+v"(lx[j]), "+v"(ly[j]), "+v"(lz[j]));
        float bv = -1.0f; int bi = 0x7fffffff;
#pragma unroll
        for (int j = 0; j < FPS_PTS; j++) {
            float dx = lx[j] - cx, dy = ly[j] - cy, dz = lz[j] - cz;
            float t0 = dx*dx, t1 = dy*dy, t2 = dz*dz;
            float d = (t0 + t1) + t2;
            float od = dl[j];
            float nd = d < od ? d : od;
            dl[j] = nd;
            if (nd > bv) { bv = nd; bi = (j << 8) + t; }
        }
        unsigned long long key = ((unsigned long long)__float_as_uint(bv) << 32)
                               | (unsigned int)(~bi);
        DPP_U64_MAX(key, 0x111);
        DPP_U64_MAX(key, 0x112);
        DPP_U64_MAX(key, 0x114);
        DPP_U64_MAX(key, 0x118);
        DPP_U64_MAX(key, 0x142);
        DPP_U64_MAX(key, 0x143);
        int p = k & 1;
        if (lane == 63) slotk[p][wid] = key;
        __syncthreads();
        ulonglong2 s01 = *(const ulonglong2*)&slotk[p][0];
        ulonglong2 s23 = *(const ulonglong2*)&slotk[p][2];
        unsigned long long kk = s01.x;
        if (s01.y > kk) kk = s01.y;
        if (s23.x > kk) kk = s23.x;
        if (s23.y > kk) kk = s23.y;
        cur = (int)(~(unsigned int)kk);
        cc = pxyz[cur];
    }
    __syncthreads();
    for (int i = t; i < M_; i += FPS_T) {
        int ix = sel[i];
        float4 q = pxyz[ix];
        fps_idx[b*M_ + i] = ix;
        out_xyz[(b*M_ + i)*3 + 0] = q.x;
        out_xyz[(b*M_ + i)*3 + 1] = q.y;
        out_xyz[(b*M_ + i)*3 + 2] = q.z;
    }
}

// ---------------- Ball query (grouped, frozen) ----------------
__global__ __launch_bounds__(256) void ballq_kernel(const float* __restrict__ xyz,
                                                    const int* __restrict__ fps_idx,
                                                    int* __restrict__ ball_idx) {
#pragma clang fp contract(off)
    __shared__ float4 pts[N_];
    __shared__ float cd[CAP];
    __shared__ int   ci[CAP];
    __shared__ int   cnt;
    __shared__ float rv[4];
    __shared__ int   ri[4];
    __shared__ int   slots[33];
    int blk = blockIdx.x;
    int b = blk >> 5;
    int g = blk & 31;
    int t = threadIdx.x;
    const float* xb = xyz + (size_t)b * N_ * 3;
    for (int i = t; i < N_; i += 256)
        pts[i] = make_float4(xb[i*3+0], xb[i*3+1], xb[i*3+2], 0.f);
    __syncthreads();
    for (int mm = 0; mm < BQ_G; mm++) {
        int m = (g << 5) + mm;
        if (t == 0) cnt = 0;
        __syncthreads();
        float4 c4 = pts[fps_idx[b*M_ + m]];
        float cx = c4.x, cy = c4.y, cz = c4.z;
        float bv = 3.4e38f; int bi = 0x7fffffff;
        for (int i = t; i < N_; i += 256) {
            float4 p = pts[i];
            float dx = p.x - cx, dy = p.y - cy, dz = p.z - cz;
            float t0 = dx*dx, t1 = dy*dy, t2 = dz*dz;
            float d = (t0 + t1) + t2;
            if (d < bv || (d == bv && i < bi)) { bv = d; bi = i; }
            if (d <= R2) {
                int pp = atomicAdd(&cnt, 1);
                if (pp < CAP) { cd[pp] = d; ci[pp] = i; }
            }
        }
        for (int off = 32; off >= 1; off >>= 1) {
            float ov = __shfl_xor(bv, off, 64);
            int   oi = __shfl_xor(bi, off, 64);
            if (ov < bv || (ov == bv && oi < bi)) { bv = ov; bi = oi; }
        }
        int w = t >> 6;
        if ((t & 63) == 0) { rv[w] = bv; ri[w] = bi; }
        __syncthreads();
        int n = cnt < CAP ? cnt : CAP;
        for (int j = t; j < n; j += 256) {
            float dj = cd[j]; int ij = ci[j];
            int rank = 0;
            for (int k = 0; k < n; k++) {
                float dk = cd[k]; int ik = ci[k];
                rank += (dk < dj) || (dk == dj && ik < ij);
            }
            if (rank < S_) slots[rank] = ij;
        }
        if (t == 0) {
            float v = rv[0]; int ix = ri[0];
            for (int j = 1; j < 4; j++)
                if (rv[j] < v || (rv[j] == v && ri[j] < ix)) { v = rv[j]; ix = ri[j]; }
            slots[32] = ix;
        }
        __syncthreads();
        if (t < S_) {
            int nearest = (n > 0) ? slots[0] : slots[32];
            int ix = (t < n) ? slots[t] : nearest;
            ball_idx[(size_t)(b*M_ + m)*S_ + t] = ix;
        }
    }
}

// ============ Staged pipeline, MCEN centers per block ============
// Weight row-pair hoisted to registers ONCE per block (was the dominant cost:
// ~17-34K uncoalesced 4B gathers per block x 16384 blocks). Inner loop per
// center identical to the proven 2-output scheme (bit-exact c-ascending dots).
// Stats partials accumulate in regs across centers; one atomic pass per block.

// S1: gather + L0 -> z0, stats0.  thread: dp=t&31 -> d{2dp,2dp+1}, sg=t>>5, s=4sg+q
__global__ __launch_bounds__(256) void mlpS1_kernel(
    const float* __restrict__ xyz, const float* __restrict__ feat,
    const int* __restrict__ fps_idx, const int* __restrict__ ball_idx,
    const float* __restrict__ w0, const float* __restrict__ b0,
    float* __restrict__ zbuf, float* __restrict__ stats) {
    __shared__ __align__(16) float xs[S_][68];   // col 67 = 0 pad
    __shared__ float rsum[64][9], rsq[64][9];
    int blk0 = blockIdx.x * MCEN, t = threadIdx.x;
    int b = blk0 >> 10;
    const float* xb = xyz + (size_t)b * N_ * 3;
    int dp = t & 31, sg = t >> 5;
    int d0 = dp * 2;
    float wA[68], wB[68];
    {
        const float* wa = w0 + (size_t)d0 * C0IN;
        const float* wb = wa + C0IN;
#pragma unroll
        for (int c = 0; c < 67; c++) { wA[c] = wa[c]; wB[c] = wb[c]; }
        wA[67] = 0.f; wB[67] = 0.f;
    }
    float bi0 = b0[d0], bi1 = b0[d0+1];
    float ls0 = 0.f, lq0 = 0.f, ls1 = 0.f, lq1 = 0.f;
    for (int e = 0; e < MCEN; e++) {
        int blk = blk0 + e;
        int m = blk & (M_ - 1);
        int cidx = fps_idx[b*M_ + m];
        float cx = xb[cidx*3+0], cy = xb[cidx*3+1], cz = xb[cidx*3+2];
        if (e) __syncthreads();              // xs reuse guard (prev compute done)
        for (int i = t; i < S_*68; i += 256) {
            int s = i / 68, c = i - s * 68;
            int p = ball_idx[(size_t)blk * S_ + s];
            float v;
            if (c == 0)       v = xb[p*3+0] - cx;
            else if (c == 1)  v = xb[p*3+1] - cy;
            else if (c == 2)  v = xb[p*3+2] - cz;
            else if (c == 67) v = 0.f;
            else              v = feat[((size_t)b*N_ + p)*IN_ + (c - 3)];
            xs[s][c] = v;
        }
        __syncthreads();                     // xs ready
        float acc0[4], acc1[4];
#pragma unroll
        for (int q = 0; q < 4; q++) { acc0[q] = bi0; acc1[q] = bi1; }
#pragma unroll
        for (int q = 0; q < 4; q++) {
            const float4* x4 = (const float4*)&xs[sg*4 + q][0];
#pragma unroll
            for (int c4 = 0; c4 < 17; c4++) {
                float4 v = x4[c4];
                acc0[q] += v.x * wA[4*c4+0]; acc1[q] += v.x * wB[4*c4+0];
                acc0[q] += v.y * wA[4*c4+1]; acc1[q] += v.y * wB[4*c4+1];
                acc0[q] += v.z * wA[4*c4+2]; acc1[q] += v.z * wB[4*c4+2];
                acc0[q] += v.w * wA[4*c4+3]; acc1[q] += v.w * wB[4*c4+3];
            }
        }
        float* zt = zbuf + (size_t)blk * 2048;
#pragma unroll
        for (int q = 0; q < 4; q++) {
            int s = sg*4 + q;
            *(float2*)&zt[s*64 + d0] = make_float2(acc0[q], acc1[q]);
            ls0 += acc0[q]; lq0 += acc0[q]*acc0[q];
            ls1 += acc1[q]; lq1 += acc1[q]*acc1[q];
        }
    }
    rsum[d0][sg] = ls0; rsq[d0][sg] = lq0;
    rsum[d0+1][sg] = ls1; rsq[d0+1][sg] = lq1;
    __syncthreads();
    if (t < 64) {
        float s = 0.f, s2 = 0.f;
#pragma unroll
        for (int j = 0; j < 8; j++) { s += rsum[t][j]; s2 += rsq[t][j]; }
        float* sb = stats + (size_t)(blockIdx.x & (NBUCK-1)) * 512;
        atomicAdd(&sb[t], s);
        atomicAdd(&sb[64 + t], s2);
    }
}

// S2: z0 -> BN0+relu -> L1 -> z1 (in-place), stats1
__global__ __launch_bounds__(256) void mlpS2_kernel(
    float* __restrict__ zbuf,
    const float* __restrict__ w1, const float* __restrict__ b1,
    const float* __restrict__ g0, const float* __restrict__ be0,
    float* __restrict__ stats) {
    __shared__ __align__(16) float y0s[S_][C0];
    __shared__ float rsum[64][9], rsq[64][9];
    __shared__ float lc[128];
    int blk0 = blockIdx.x * MCEN, t = threadIdx.x;
    const float inv_n = 1.0f / (float)NTOT;
    if (t < 64) {
        float s = 0.f, s2 = 0.f;
        for (int j = 0; j < NBUCK; j++) { s += stats[j*512 + t]; s2 += stats[j*512 + 64 + t]; }
        float mean = s * inv_n, var = s2 * inv_n - mean * mean;
        float a = g0[t] * (1.0f / sqrtf(var + 1e-5f));
        lc[t] = a; lc[64 + t] = be0[t] - mean * a;
    }
    int dc = t & 63;
    int dp = t & 31, sg = t >> 5;
    int d0 = dp * 2;
    float wA[64], wB[64];
    {
        const float4* wa4 = (const float4*)(w1 + (size_t)d0 * C0);
        const float4* wb4 = (const float4*)(w1 + (size_t)(d0+1) * C0);
#pragma unroll
        for (int c4 = 0; c4 < 16; c4++) {
            float4 a = wa4[c4], bb = wb4[c4];
            wA[4*c4+0] = a.x;  wA[4*c4+1] = a.y;  wA[4*c4+2] = a.z;  wA[4*c4+3] = a.w;
            wB[4*c4+0] = bb.x; wB[4*c4+1] = bb.y; wB[4*c4+2] = bb.z; wB[4*c4+3] = bb.w;
        }
    }
    float bi0 = b1[d0], bi1 = b1[d0+1];
    __syncthreads();   // lc ready
    float a0c = lc[dc], c0c = lc[64 + dc];
    float ls0 = 0.f, lq0 = 0.f, ls1 = 0.f, lq1 = 0.f;
    for (int e = 0; e < MCEN; e++) {
        int blk = blk0 + e;
        float* zt = zbuf + (size_t)blk * 2048;
        float zv[8];
#pragma unroll
        for (int j = 0; j < 8; j++) zv[j] = zt[t + 256*j];
        if (e) __syncthreads();              // y0s reuse guard
#pragma unroll
        for (int j = 0; j < 8; j++) {
            float v = zv[j] * a0c + c0c;
            y0s[(t >> 6) + 4*j][dc] = v > 0.f ? v : 0.f;
        }
        __syncthreads();                     // y0s ready
        float acc0[4], acc1[4];
#pragma unroll
        for (int q = 0; q < 4; q++) { acc0[q] = bi0; acc1[q] = bi1; }
#pragma unroll
        for (int q = 0; q < 4; q++) {
            const float4* x4 = (const float4*)&y0s[sg*4 + q][0];
#pragma unroll
            for (int c4 = 0; c4 < 16; c4++) {
                float4 v = x4[c4];
                acc0[q] += v.x * wA[4*c4+0]; acc1[q] += v.x * wB[4*c4+0];
                acc0[q] += v.y * wA[4*c4+1]; acc1[q] += v.y * wB[4*c4+1];
                acc0[q] += v.z * wA[4*c4+2]; acc1[q] += v.z * wB[4*c4+2];
                acc0[q] += v.w * wA[4*c4+3]; acc1[q] += v.w * wB[4*c4+3];
            }
        }
#pragma unroll
        for (int q = 0; q < 4; q++) {
            int s = sg*4 + q;
            *(float2*)&zt[s*64 + d0] = make_float2(acc0[q], acc1[q]);
            ls0 += acc0[q]; lq0 += acc0[q]*acc0[q];
            ls1 += acc1[q]; lq1 += acc1[q]*acc1[q];
        }
    }
    rsum[d0][sg] = ls0; rsq[d0][sg] = lq0;
    rsum[d0+1][sg] = ls1; rsq[d0+1][sg] = lq1;
    __syncthreads();
    if (t < 64) {
        float s = 0.f, s2 = 0.f;
#pragma unroll
        for (int j = 0; j < 8; j++) { s += rsum[t][j]; s2 += rsq[t][j]; }
        float* sb = stats + (size_t)(blockIdx.x & (NBUCK-1)) * 512;
        atomicAdd(&sb[128 + t], s);
        atomicAdd(&sb[192 + t], s2);
    }
}

// S3: z1 -> BN1+relu -> L2 -> stats2 (+ optional z2 store)
// thread: dp=t&63 -> d{2dp,2dp+1}, sg=t>>6, s=8sg+q
template<int STOREZ>
__global__ __launch_bounds__(256) void mlpS3_kernel(
    const float* __restrict__ zbuf,
    const float* __restrict__ w2, const float* __restrict__ b2,
    const float* __restrict__ g1, const float* __restrict__ be1,
    float* __restrict__ z2buf, float* __restrict__ stats) {
    __shared__ __align__(16) float y1s[S_][C1];
    __shared__ float rsum[128][5], rsq[128][5];
    __shared__ float lc[128];
    int blk0 = blockIdx.x * MCEN, t = threadIdx.x;
    const float inv_n = 1.0f / (float)NTOT;
    if (t < 64) {
        float s = 0.f, s2 = 0.f;
        for (int j = 0; j < NBUCK; j++) { s += stats[j*512 + 128 + t]; s2 += stats[j*512 + 192 + t]; }
        float mean = s * inv_n, var = s2 * inv_n - mean * mean;
        float a = g1[t] * (1.0f / sqrtf(var + 1e-5f));
        lc[t] = a; lc[64 + t] = be1[t] - mean * a;
    }
    int dc = t & 63;
    int dp = t & 63, sg = t >> 6;
    int d0 = dp * 2;
    float wA[64], wB[64];
    {
        const float4* wa4 = (const float4*)(w2 + (size_t)d0 * C1);
        const float4* wb4 = (const float4*)(w2 + (size_t)(d0+1) * C1);
#pragma unroll
        for (int c4 = 0; c4 < 16; c4++) {
            float4 a = wa4[c4], bb = wb4[c4];
            wA[4*c4+0] = a.x;  wA[4*c4+1] = a.y;  wA[4*c4+2] = a.z;  wA[4*c4+3] = a.w;
            wB[4*c4+0] = bb.x; wB[4*c4+1] = bb.y; wB[4*c4+2] = bb.z; wB[4*c4+3] = bb.w;
        }
    }
    float bi0 = b2[d0], bi1 = b2[d0+1];
    __syncthreads();   // lc ready
    float a1c = lc[dc], c1c = lc[64 + dc];
    float ls0 = 0.f, lq0 = 0.f, ls1 = 0.f, lq1 = 0.f;
    for (int e = 0; e < MCEN; e++) {
        int blk = blk0 + e;
        const float* zt = zbuf + (size_t)blk * 2048;
        float zv[8];
#pragma unroll
        for (int j = 0; j < 8; j++) zv[j] = zt[t + 256*j];
        if (e) __syncthreads();              // y1s reuse guard
#pragma unroll
        for (int j = 0; j < 8; j++) {
            float v = zv[j] * a1c + c1c;
            y1s[(t >> 6) + 4*j][dc] = v > 0.f ? v : 0.f;
        }
        __syncthreads();                     // y1s ready
        float acc0[8], acc1[8];
#pragma unroll
        for (int q = 0; q < 8; q++) { acc0[q] = bi0; acc1[q] = bi1; }
#pragma unroll
        for (int q = 0; q < 8; q++) {
            const float4* x4 = (const float4*)&y1s[sg*8 + q][0];
#pragma unroll
            for (int c4 = 0; c4 < 16; c4++) {
                float4 v = x4[c4];
                acc0[q] += v.x * wA[4*c4+0]; acc1[q] += v.x * wB[4*c4+0];
                acc0[q] += v.y * wA[4*c4+1]; acc1[q] += v.y * wB[4*c4+1];
                acc0[q] += v.z * wA[4*c4+2]; acc1[q] += v.z * wB[4*c4+2];
                acc0[q] += v.w * wA[4*c4+3]; acc1[q] += v.w * wB[4*c4+3];
            }
        }
        float* z2t = z2buf + (size_t)blk * 4096;
#pragma unroll
        for (int q = 0; q < 8; q++) {
            if (STOREZ) {
                int s = sg*8 + q;
                *(float2*)&z2t[s*128 + d0] = make_float2(acc0[q], acc1[q]);
            }
            ls0 += acc0[q]; lq0 += acc0[q]*acc0[q];
            ls1 += acc1[q]; lq1 += acc1[q]*acc1[q];
        }
    }
    rsum[d0][sg] = ls0; rsq[d0][sg] = lq0;
    rsum[d0+1][sg] = ls1; rsq[d0+1][sg] = lq1;
    __syncthreads();
    if (t < 128) {
        float s = 0.f, s2 = 0.f;
#pragma unroll
        for (int j = 0; j < 4; j++) { s += rsum[t][j]; s2 += rsq[t][j]; }
        float* sb = stats + (size_t)(blockIdx.x & (NBUCK-1)) * 512;
        atomicAdd(&sb[256 + t], s);
        atomicAdd(&sb[384 + t], s2);
    }
}

// S4z: z2 -> BN2+relu -> max -> out (streaming; used when z2 staged)
__global__ __launch_bounds__(256) void mlpS4z_kernel(
    const float* __restrict__ z2buf,
    const float* __restrict__ g2, const float* __restrict__ be2,
    const float* __restrict__ stats, float* __restrict__ out_feat) {
    __shared__ float red[256];
    __shared__ float lc[256];
    int blk = blockIdx.x, t = threadIdx.x;
    const float inv_n = 1.0f / (float)NTOT;
    if (t < 128) {
        float s = 0.f, s2 = 0.f;
        for (int j = 0; j < NBUCK; j++) { s += stats[j*512 + 256 + t]; s2 += stats[j*512 + 384 + t]; }
        float mean = s * inv_n, var = s2 * inv_n - mean * mean;
        float a = g2[t] * (1.0f / sqrtf(var + 1e-5f));
        lc[t] = a; lc[128 + t] = be2[t] - mean * a;
    }
    const float* z2t = z2buf + (size_t)blk * 4096;
    float zv[16];
#pragma unroll
    for (int j = 0; j < 16; j++) zv[j] = z2t[t + 256*j];
    __syncthreads();
    int d = t & 127;
    float a2 = lc[d], c2 = lc[128 + d];
    float lmax = -3.4e38f;
#pragma unroll
    for (int j = 0; j < 16; j++) {
        float v = zv[j] * a2 + c2;
        v = v > 0.f ? v : 0.f;
        lmax = v > lmax ? v : lmax;
    }
    red[t] = lmax;
    __syncthreads();
    if (t < 128) {
        float v = red[t] > red[t+128] ? red[t] : red[t+128];
        out_feat[(size_t)blk * C2 + t] = v;
    }
}

// S4r: recompute fallback (no z2 space): z1 -> BN1+relu -> L2 -> BN2+relu -> max
__global__ __launch_bounds__(256) void mlpS4r_kernel(
    const float* __restrict__ zbuf,
    const float* __restrict__ w2, const float* __restrict__ b2,
    const float* __restrict__ g1, const float* __restrict__ be1,
    const float* __restrict__ g2, const float* __restrict__ be2,
    const float* __restrict__ stats, float* __restrict__ out_feat) {
    __shared__ __align__(16) float y1s[S_][C1];
    __shared__ float rmax[128][5];
    __shared__ float lc[384];   // [a1 64|c1 64|a2 128|c2 128]
    int blk0 = blockIdx.x * MCEN, t = threadIdx.x;
    const float inv_n = 1.0f / (float)NTOT;
    if (t < 64) {
        float s = 0.f, s2 = 0.f;
        for (int j = 0; j < NBUCK; j++) { s += stats[j*512 + 128 + t]; s2 += stats[j*512 + 192 + t]; }
        float mean = s * inv_n, var = s2 * inv_n - mean * mean;
        float a = g1[t] * (1.0f / sqrtf(var + 1e-5f));
        lc[t] = a; lc[64 + t] = be1[t] - mean * a;
    }
    if (t < 128) {
        float s = 0.f, s2 = 0.f;
        for (int j = 0; j < NBUCK; j++) { s += stats[j*512 + 256 + t]; s2 += stats[j*512 + 384 + t]; }
        float mean = s * inv_n, var = s2 * inv_n - mean * mean;
        float a = g2[t] * (1.0f / sqrtf(var + 1e-5f));
        lc[128 + t] = a; lc[256 + t] = be2[t] - mean * a;
    }
    int dc = t & 63;
    int dp = t & 63, sg = t >> 6;
    int d0 = dp * 2;
    float wA[64], wB[64];
    {
        const float4* wa4 = (const float4*)(w2 + (size_t)d0 * C1);
        const float4* wb4 = (const float4*)(w2 + (size_t)(d0+1) * C1);
#pragma unroll
        for (int c4 = 0; c4 < 16; c4++) {
            float4 a = wa4[c4], bb = wb4[c4];
            wA[4*c4+0] = a.x;  wA[4*c4+1] = a.y;  wA[4*c4+2] = a.z;  wA[4*c4+3] = a.w;
            wB[4*c4+0] = bb.x; wB[4*c4+1] = bb.y; wB[4*c4+2] = bb.z; wB[4*c4+3] = bb.w;
        }
    }
    float bi0 = b2[d0], bi1 = b2[d0+1];
    __syncthreads();   // lc ready
    float a1c = lc[dc], c1c = lc[64 + dc];
    float a20 = lc[128 + d0], c20 = lc[256 + d0];
    float a21 = lc[128 + d0 + 1], c21 = lc[256 + d0 + 1];
    for (int e = 0; e < MCEN; e++) {
        int blk = blk0 + e;
        const float* zt = zbuf + (size_t)blk * 2048;
        float zv[8];
#pragma unroll
        for (int j = 0; j < 8; j++) zv[j] = zt[t + 256*j];
        if (e) __syncthreads();              // y1s/rmax reuse guard
#pragma unroll
        for (int j = 0; j < 8; j++) {
            float v = zv[j] * a1c + c1c;
            y1s[(t >> 6) + 4*j][dc] = v > 0.f ? v : 0.f;
        }
        __syncthreads();                     // y1s ready
        float acc0[8], acc1[8];
#pragma unroll
        for (int q = 0; q < 8; q++) { acc0[q] = bi0; acc1[q] = bi1; }
#pragma unroll
        for (int q = 0; q < 8; q++) {
            const float4* x4 = (const float4*)&y1s[sg*8 + q][0];
#pragma unroll
            for (int c4 = 0; c4 < 16; c4++) {
                float4 v = x4[c4];
                acc0[q] += v.x * wA[4*c4+0]; acc1[q] += v.x * wB[4*c4+0];
                acc0[q] += v.y * wA[4*c4+1]; acc1[q] += v.y * wB[4*c4+1];
                acc0[q] += v.z * wA[4*c4+2]; acc1[q] += v.z * wB[4*c4+2];
                acc0[q] += v.w * wA[4*c4+3]; acc1[q] += v.w * wB[4*c4+3];
            }
        }
        float lm0 = -3.4e38f, lm1 = -3.4e38f;
#pragma unroll
        for (int q = 0; q < 8; q++) {
            float v0 = acc0[q] * a20 + c20; v0 = v0 > 0.f ? v0 : 0.f;
            float v1 = acc1[q] * a21 + c21; v1 = v1 > 0.f ? v1 : 0.f;
            lm0 = v0 > lm0 ? v0 : lm0;
            lm1 = v1 > lm1 ? v1 : lm1;
        }
        rmax[d0][sg] = lm0; rmax[d0+1][sg] = lm1;
        __syncthreads();                     // rmax ready
        if (t < 128) {
            float v = rmax[t][0];
#pragma unroll
            for (int j = 1; j < 4; j++) v = rmax[t][j] > v ? rmax[t][j] : v;
            out_feat[(size_t)blk * C2 + t] = v;
        }
    }
}

extern "C" void kernel_launch(void* const* d_in, const int* in_sizes, int n_in,
                              void* d_out, int out_size, void* d_ws, size_t ws_size,
                              hipStream_t stream) {
    const float* xyz  = (const float*)d_in[0];
    const float* feat = (const float*)d_in[1];
    const float* w0 = (const float*)d_in[2];  const float* b0 = (const float*)d_in[3];
    const float* g0 = (const float*)d_in[4];  const float* be0 = (const float*)d_in[5];
    const float* w1 = (const float*)d_in[6];  const float* b1 = (const float*)d_in[7];
    const float* g1 = (const float*)d_in[8];  const float* be1 = (const float*)d_in[9];
    const float* w2 = (const float*)d_in[10]; const float* b2 = (const float*)d_in[11];
    const float* g2 = (const float*)d_in[12]; const float* be2 = (const float*)d_in[13];
    float* out_xyz  = (float*)d_out;
    float* out_feat = out_xyz + B_*M_*3;

    int* fps_i  = (int*)d_ws;                                   // 64 KB
    int* ball_i = (int*)((char*)d_ws + 65536);                  // 2 MB
    float* stats = (float*)((char*)d_ws + 65536 + 2097152);     // 32 KB
    size_t zoff = 65536 + 2097152 + (size_t)NBUCK*512*4;
    float* zbuf = (float*)((char*)d_ws + zoff);                 // 128 MB (fits: round 6 proved ws >= 137 MB)
    float* z2buf = zbuf + (size_t)B_*M_ * 2048;                 // +256 MB (guarded)
    size_t need2 = zoff + (size_t)B_*M_ * 2048 * 4 + (size_t)B_*M_ * 4096 * 4;
    bool stage_z2 = ws_size >= need2;

    hipMemsetAsync(stats, 0, NBUCK*512*sizeof(float), stream);
    fps_kernel<<<B_, FPS_T, 0, stream>>>(xyz, fps_i, out_xyz);
    ballq_kernel<<<B_ * (M_/BQ_G), 256, 0, stream>>>(xyz, fps_i, ball_i);
    mlpS1_kernel<<<(B_*M_)/MCEN, 256, 0, stream>>>(xyz, feat, fps_i, ball_i, w0, b0, zbuf, stats);
    mlpS2_kernel<<<(B_*M_)/MCEN, 256, 0, stream>>>(zbuf, w1, b1, g0, be0, stats);
    if (stage_z2) {
        mlpS3_kernel<1><<<(B_*M_)/MCEN, 256, 0, stream>>>(zbuf, w2, b2, g1, be1, z2buf, stats);
        mlpS4z_kernel<<<B_*M_, 256, 0, stream>>>(z2buf, g2, be2, stats, out_feat);
    } else {
        mlpS3_kernel<0><<<(B_*M_)/MCEN, 256, 0, stream>>>(zbuf, w2, b2, g1, be1, z2buf, stats);
        mlpS4r_kernel<<<(B_*M_)/MCEN, 256, 0, stream>>>(zbuf, w2, b2, g1, be1, g2, be2, stats, out_feat);
    }
}

// Round 10
// 1460.669 us; speedup vs baseline: 1.2896x; 1.1118x over previous
//
#include <hip/hip_runtime.h>

#define B_ 16
#define N_ 4096
#define M_ 1024
#define S_ 32
#define IN_ 64
#define C0IN 67
#define C0 64
#define C1 64
#define C2 128
#define NTOT (B_*M_*S_)
#define R2 0.04f
#define CAP 1024
#define NBUCK 16
#define BQ_G 32
#define MCEN 16   // centers per MLP block: weight regs amortized 16x

#define FPS_T 256
#define FPS_PTS 16

// 64-bit DPP max (packed key).
#define DPP_U64_MAX(k, ctrl) { \
    unsigned int _lo = (unsigned int)(k), _hi = (unsigned int)((k) >> 32); \
    unsigned int _olo = (unsigned int)__builtin_amdgcn_update_dpp((int)_lo, (int)_lo, ctrl, 0xF, 0xF, false); \
    unsigned int _ohi = (unsigned int)__builtin_amdgcn_update_dpp((int)_hi, (int)_hi, ctrl, 0xF, 0xF, false); \
    unsigned long long _o = ((unsigned long long)_ohi << 32) | _olo; \
    if (_o > (k)) (k) = _o; }

// ---------------- FPS ---------------- (frozen, proven 662-665 us)
__global__ __launch_bounds__(FPS_T, 1) void fps_kernel(const float* __restrict__ xyz,
                                                       int* __restrict__ fps_idx,
                                                       float* __restrict__ out_xyz) {
#pragma clang fp contract(off)
    __shared__ float4 pxyz[N_];
    __shared__ int    sel[M_];
    __shared__ __align__(16) unsigned long long slotk[2][4];
    int b = blockIdx.x, t = threadIdx.x;
    const float* xb = xyz + (size_t)b * N_ * 3;
    float lx[FPS_PTS], ly[FPS_PTS], lz[FPS_PTS], dl[FPS_PTS];
#pragma unroll
    for (int j = 0; j < FPS_PTS; j++) {
        int i = (j << 8) + t;
        float x = xb[3*i], y = xb[3*i+1], z = xb[3*i+2];
        lx[j] = x; ly[j] = y; lz[j] = z;
        dl[j] = __builtin_inff();
        pxyz[i] = make_float4(x, y, z, 0.f);
    }
    __syncthreads();
    int wid = t >> 6, lane = t & 63;
    int cur = 0;
    float4 cc = pxyz[0];
    for (int k = 0; k < M_; k++) {
        float cx = cc.x, cy = cc.y, cz = cc.z;
        if (t == 0) sel[k] = cur;
#pragma unroll
        for (int j = 0; j < FPS_PTS; j++)
            asm volatile("" : "+v"(lx[j]), "+v"(ly[j]), "+v"(lz[j]));
        float bv = -1.0f; int bi = 0x7fffffff;
#pragma unroll
        for (int j = 0; j < FPS_PTS; j++) {
            float dx = lx[j] - cx, dy = ly[j] - cy, dz = lz[j] - cz;
            float t0 = dx*dx, t1 = dy*dy, t2 = dz*dz;
            float d = (t0 + t1) + t2;
            float od = dl[j];
            float nd = d < od ? d : od;
            dl[j] = nd;
            if (nd > bv) { bv = nd; bi = (j << 8) + t; }
        }
        unsigned long long key = ((unsigned long long)__float_as_uint(bv) << 32)
                               | (unsigned int)(~bi);
        DPP_U64_MAX(key, 0x111);
        DPP_U64_MAX(key, 0x112);
        DPP_U64_MAX(key, 0x114);
        DPP_U64_MAX(key, 0x118);
        DPP_U64_MAX(key, 0x142);
        DPP_U64_MAX(key, 0x143);
        int p = k & 1;
        if (lane == 63) slotk[p][wid] = key;
        __syncthreads();
        ulonglong2 s01 = *(const ulonglong2*)&slotk[p][0];
        ulonglong2 s23 = *(const ulonglong2*)&slotk[p][2];
        unsigned long long kk = s01.x;
        if (s01.y > kk) kk = s01.y;
        if (s23.x > kk) kk = s23.x;
        if (s23.y > kk) kk = s23.y;
        cur = (int)(~(unsigned int)kk);
        cc = pxyz[cur];
    }
    __syncthreads();
    for (int i = t; i < M_; i += FPS_T) {
        int ix = sel[i];
        float4 q = pxyz[ix];
        fps_idx[b*M_ + i] = ix;
        out_xyz[(b*M_ + i)*3 + 0] = q.x;
        out_xyz[(b*M_ + i)*3 + 1] = q.y;
        out_xyz[(b*M_ + i)*3 + 2] = q.z;
    }
}

// ---------------- Ball query (grouped, frozen) ----------------
__global__ __launch_bounds__(256) void ballq_kernel(const float* __restrict__ xyz,
                                                    const int* __restrict__ fps_idx,
                                                    int* __restrict__ ball_idx) {
#pragma clang fp contract(off)
    __shared__ float4 pts[N_];
    __shared__ float cd[CAP];
    __shared__ int   ci[CAP];
    __shared__ int   cnt;
    __shared__ float rv[4];
    __shared__ int   ri[4];
    __shared__ int   slots[33];
    int blk = blockIdx.x;
    int b = blk >> 5;
    int g = blk & 31;
    int t = threadIdx.x;
    const float* xb = xyz + (size_t)b * N_ * 3;
    for (int i = t; i < N_; i += 256)
        pts[i] = make_float4(xb[i*3+0], xb[i*3+1], xb[i*3+2], 0.f);
    __syncthreads();
    for (int mm = 0; mm < BQ_G; mm++) {
        int m = (g << 5) + mm;
        if (t == 0) cnt = 0;
        __syncthreads();
        float4 c4 = pts[fps_idx[b*M_ + m]];
        float cx = c4.x, cy = c4.y, cz = c4.z;
        float bv = 3.4e38f; int bi = 0x7fffffff;
        for (int i = t; i < N_; i += 256) {
            float4 p = pts[i];
            float dx = p.x - cx, dy = p.y - cy, dz = p.z - cz;
            float t0 = dx*dx, t1 = dy*dy, t2 = dz*dz;
            float d = (t0 + t1) + t2;
            if (d < bv || (d == bv && i < bi)) { bv = d; bi = i; }
            if (d <= R2) {
                int pp = atomicAdd(&cnt, 1);
                if (pp < CAP) { cd[pp] = d; ci[pp] = i; }
            }
        }
        for (int off = 32; off >= 1; off >>= 1) {
            float ov = __shfl_xor(bv, off, 64);
            int   oi = __shfl_xor(bi, off, 64);
            if (ov < bv || (ov == bv && oi < bi)) { bv = ov; bi = oi; }
        }
        int w = t >> 6;
        if ((t & 63) == 0) { rv[w] = bv; ri[w] = bi; }
        __syncthreads();
        int n = cnt < CAP ? cnt : CAP;
        for (int j = t; j < n; j += 256) {
            float dj = cd[j]; int ij = ci[j];
            int rank = 0;
            for (int k = 0; k < n; k++) {
                float dk = cd[k]; int ik = ci[k];
                rank += (dk < dj) || (dk == dj && ik < ij);
            }
            if (rank < S_) slots[rank] = ij;
        }
        if (t == 0) {
            float v = rv[0]; int ix = ri[0];
            for (int j = 1; j < 4; j++)
                if (rv[j] < v || (rv[j] == v && ri[j] < ix)) { v = rv[j]; ix = ri[j]; }
            slots[32] = ix;
        }
        __syncthreads();
        if (t < S_) {
            int nearest = (n > 0) ? slots[0] : slots[32];
            int ix = (t < n) ? slots[t] : nearest;
            ball_idx[(size_t)(b*M_ + m)*S_ + t] = ix;
        }
    }
}

// ============ Staged pipeline, MCEN centers per block ============
// S1 layout: xs[s][72] = [Dxyz(3) | 0 | feat(64, 16B-aligned) | 0 x4].
// Weight regs padded identically -> dot over c=0..71 has the SAME relative
// order of real terms plus exact +0 terms => bit-identical to prior rounds.
// Feat gathered via float4 + ds_write_b128 (was 2048 scalar loads + div-by-68).

// S1: gather + L0 -> z0, stats0.  thread: dp=t&31 -> d{2dp,2dp+1}, sg=t>>5
__global__ __launch_bounds__(256) void mlpS1_kernel(
    const float* __restrict__ xyz, const float* __restrict__ feat,
    const int* __restrict__ fps_idx, const int* __restrict__ ball_idx,
    const float* __restrict__ w0, const float* __restrict__ b0,
    float* __restrict__ zbuf, float* __restrict__ stats) {
    __shared__ __align__(16) float xs[S_][72];
    __shared__ float rsum[64][9], rsq[64][9];
    __shared__ int idxs[S_];
    int blk0 = blockIdx.x * MCEN, t = threadIdx.x;
    int b = blk0 >> 10;
    const float* xb = xyz + (size_t)b * N_ * 3;
    int dp = t & 31, sg = t >> 5;
    int d0 = dp * 2;
    // weight rows, padded to match xs layout
    float wA[72], wB[72];
    {
        const float* wa = w0 + (size_t)d0 * C0IN;
        const float* wb = wa + C0IN;
        wA[0] = wa[0]; wA[1] = wa[1]; wA[2] = wa[2]; wA[3] = 0.f;
        wB[0] = wb[0]; wB[1] = wb[1]; wB[2] = wb[2]; wB[3] = 0.f;
#pragma unroll
        for (int c = 0; c < 64; c++) { wA[4 + c] = wa[3 + c]; wB[4 + c] = wb[3 + c]; }
#pragma unroll
        for (int c = 68; c < 72; c++) { wA[c] = 0.f; wB[c] = 0.f; }
    }
    float bi0 = b0[d0], bi1 = b0[d0+1];
    // constant pads written once (never overwritten by per-center fills)
    if (t < 32) { xs[t][3] = 0.f; }
    else if (t < 160) { int s = (t - 32) >> 2; xs[s][68 + ((t - 32) & 3)] = 0.f; }
    float ls0 = 0.f, lq0 = 0.f, ls1 = 0.f, lq1 = 0.f;
    for (int e = 0; e < MCEN; e++) {
        int blk = blk0 + e;
        int m = blk & (M_ - 1);
        int cidx = fps_idx[b*M_ + m];
        float cx = xb[cidx*3+0], cy = xb[cidx*3+1], cz = xb[cidx*3+2];
        if (t < S_) idxs[t] = ball_idx[(size_t)blk * S_ + t];
        __syncthreads();                     // idxs ready + xs reuse guard
        // feat: 512 float4 per center, 2 per thread
#pragma unroll
        for (int ii = 0; ii < 2; ii++) {
            int i = t + ii * 256;
            int s = i >> 4, c4 = i & 15;
            int p = idxs[s];
            float4 v = *(const float4*)&feat[((size_t)b*N_ + p)*IN_ + 4*c4];
            *(float4*)&xs[s][4 + 4*c4] = v;
        }
        // xyz: 96 elements
        if (t < 96) {
            int s = t >> 2, comp = t & 3;    // comp 0..2 used, 3 skipped below
            if (comp < 3) {
                int p = idxs[s];
                float v = (comp == 0) ? xb[p*3+0] - cx
                        : (comp == 1) ? xb[p*3+1] - cy
                                      : xb[p*3+2] - cz;
                xs[s][comp] = v;
            }
        } else if (t < 224) {
            int tt = t - 96;
            int s = 24 + (tt >> 2), comp = tt & 3;
            if (comp < 3 && s < 32) {
                int p = idxs[s];
                float v = (comp == 0) ? xb[p*3+0] - cx
                        : (comp == 1) ? xb[p*3+1] - cy
                                      : xb[p*3+2] - cz;
                xs[s][comp] = v;
            }
        }
        __syncthreads();                     // xs ready
        float acc0[4], acc1[4];
#pragma unroll
        for (int q = 0; q < 4; q++) { acc0[q] = bi0; acc1[q] = bi1; }
#pragma unroll
        for (int q = 0; q < 4; q++) {
            const float4* x4 = (const float4*)&xs[sg*4 + q][0];
#pragma unroll
            for (int c4 = 0; c4 < 18; c4++) {
                float4 v = x4[c4];
                acc0[q] += v.x * wA[4*c4+0]; acc1[q] += v.x * wB[4*c4+0];
                acc0[q] += v.y * wA[4*c4+1]; acc1[q] += v.y * wB[4*c4+1];
                acc0[q] += v.z * wA[4*c4+2]; acc1[q] += v.z * wB[4*c4+2];
                acc0[q] += v.w * wA[4*c4+3]; acc1[q] += v.w * wB[4*c4+3];
            }
        }
        float* zt = zbuf + (size_t)blk * 2048;
#pragma unroll
        for (int q = 0; q < 4; q++) {
            int s = sg*4 + q;
            *(float2*)&zt[s*64 + d0] = make_float2(acc0[q], acc1[q]);
            ls0 += acc0[q]; lq0 += acc0[q]*acc0[q];
            ls1 += acc1[q]; lq1 += acc1[q]*acc1[q];
        }
    }
    rsum[d0][sg] = ls0; rsq[d0][sg] = lq0;
    rsum[d0+1][sg] = ls1; rsq[d0+1][sg] = lq1;
    __syncthreads();
    if (t < 64) {
        float s = 0.f, s2 = 0.f;
#pragma unroll
        for (int j = 0; j < 8; j++) { s += rsum[t][j]; s2 += rsq[t][j]; }
        float* sb = stats + (size_t)(blockIdx.x & (NBUCK-1)) * 512;
        atomicAdd(&sb[t], s);
        atomicAdd(&sb[64 + t], s2);
    }
}

// S2: z0 -> BN0+relu -> L1 -> z1 (in-place), stats1
__global__ __launch_bounds__(256) void mlpS2_kernel(
    float* __restrict__ zbuf,
    const float* __restrict__ w1, const float* __restrict__ b1,
    const float* __restrict__ g0, const float* __restrict__ be0,
    float* __restrict__ stats) {
    __shared__ __align__(16) float y0s[S_][C0];
    __shared__ float rsum[64][9], rsq[64][9];
    __shared__ float lc[128];
    int blk0 = blockIdx.x * MCEN, t = threadIdx.x;
    const float inv_n = 1.0f / (float)NTOT;
    if (t < 64) {
        float s = 0.f, s2 = 0.f;
        for (int j = 0; j < NBUCK; j++) { s += stats[j*512 + t]; s2 += stats[j*512 + 64 + t]; }
        float mean = s * inv_n, var = s2 * inv_n - mean * mean;
        float a = g0[t] * (1.0f / sqrtf(var + 1e-5f));
        lc[t] = a; lc[64 + t] = be0[t] - mean * a;
    }
    int dc = t & 63;
    int dp = t & 31, sg = t >> 5;
    int d0 = dp * 2;
    float wA[64], wB[64];
    {
        const float4* wa4 = (const float4*)(w1 + (size_t)d0 * C0);
        const float4* wb4 = (const float4*)(w1 + (size_t)(d0+1) * C0);
#pragma unroll
        for (int c4 = 0; c4 < 16; c4++) {
            float4 a = wa4[c4], bb = wb4[c4];
            wA[4*c4+0] = a.x;  wA[4*c4+1] = a.y;  wA[4*c4+2] = a.z;  wA[4*c4+3] = a.w;
            wB[4*c4+0] = bb.x; wB[4*c4+1] = bb.y; wB[4*c4+2] = bb.z; wB[4*c4+3] = bb.w;
        }
    }
    float bi0 = b1[d0], bi1 = b1[d0+1];
    __syncthreads();   // lc ready
    float a0c = lc[dc], c0c = lc[64 + dc];
    float ls0 = 0.f, lq0 = 0.f, ls1 = 0.f, lq1 = 0.f;
    for (int e = 0; e < MCEN; e++) {
        int blk = blk0 + e;
        float* zt = zbuf + (size_t)blk * 2048;
        float zv[8];
#pragma unroll
        for (int j = 0; j < 8; j++) zv[j] = zt[t + 256*j];
        if (e) __syncthreads();              // y0s reuse guard
#pragma unroll
        for (int j = 0; j < 8; j++) {
            float v = zv[j] * a0c + c0c;
            y0s[(t >> 6) + 4*j][dc] = v > 0.f ? v : 0.f;
        }
        __syncthreads();                     // y0s ready
        float acc0[4], acc1[4];
#pragma unroll
        for (int q = 0; q < 4; q++) { acc0[q] = bi0; acc1[q] = bi1; }
#pragma unroll
        for (int q = 0; q < 4; q++) {
            const float4* x4 = (const float4*)&y0s[sg*4 + q][0];
#pragma unroll
            for (int c4 = 0; c4 < 16; c4++) {
                float4 v = x4[c4];
                acc0[q] += v.x * wA[4*c4+0]; acc1[q] += v.x * wB[4*c4+0];
                acc0[q] += v.y * wA[4*c4+1]; acc1[q] += v.y * wB[4*c4+1];
                acc0[q] += v.z * wA[4*c4+2]; acc1[q] += v.z * wB[4*c4+2];
                acc0[q] += v.w * wA[4*c4+3]; acc1[q] += v.w * wB[4*c4+3];
            }
        }
#pragma unroll
        for (int q = 0; q < 4; q++) {
            int s = sg*4 + q;
            *(float2*)&zt[s*64 + d0] = make_float2(acc0[q], acc1[q]);
            ls0 += acc0[q]; lq0 += acc0[q]*acc0[q];
            ls1 += acc1[q]; lq1 += acc1[q]*acc1[q];
        }
    }
    rsum[d0][sg] = ls0; rsq[d0][sg] = lq0;
    rsum[d0+1][sg] = ls1; rsq[d0+1][sg] = lq1;
    __syncthreads();
    if (t < 64) {
        float s = 0.f, s2 = 0.f;
#pragma unroll
        for (int j = 0; j < 8; j++) { s += rsum[t][j]; s2 += rsq[t][j]; }
        float* sb = stats + (size_t)(blockIdx.x & (NBUCK-1)) * 512;
        atomicAdd(&sb[128 + t], s);
        atomicAdd(&sb[192 + t], s2);
    }
}

// S3: z1 -> BN1+relu -> L2 -> stats2 (+ optional z2 store)
template<int STOREZ>
__global__ __launch_bounds__(256) void mlpS3_kernel(
    const float* __restrict__ zbuf,
    const float* __restrict__ w2, const float* __restrict__ b2,
    const float* __restrict__ g1, const float* __restrict__ be1,
    float* __restrict__ z2buf, float* __restrict__ stats) {
    __shared__ __align__(16) float y1s[S_][C1];
    __shared__ float rsum[128][5], rsq[128][5];
    __shared__ float lc[128];
    int blk0 = blockIdx.x * MCEN, t = threadIdx.x;
    const float inv_n = 1.0f / (float)NTOT;
    if (t < 64) {
        float s = 0.f, s2 = 0.f;
        for (int j = 0; j < NBUCK; j++) { s += stats[j*512 + 128 + t]; s2 += stats[j*512 + 192 + t]; }
        float mean = s * inv_n, var = s2 * inv_n - mean * mean;
        float a = g1[t] * (1.0f / sqrtf(var + 1e-5f));
        lc[t] = a; lc[64 + t] = be1[t] - mean * a;
    }
    int dc = t & 63;
    int dp = t & 63, sg = t >> 6;
    int d0 = dp * 2;
    float wA[64], wB[64];
    {
        const float4* wa4 = (const float4*)(w2 + (size_t)d0 * C1);
        const float4* wb4 = (const float4*)(w2 + (size_t)(d0+1) * C1);
#pragma unroll
        for (int c4 = 0; c4 < 16; c4++) {
            float4 a = wa4[c4], bb = wb4[c4];
            wA[4*c4+0] = a.x;  wA[4*c4+1] = a.y;  wA[4*c4+2] = a.z;  wA[4*c4+3] = a.w;
            wB[4*c4+0] = bb.x; wB[4*c4+1] = bb.y; wB[4*c4+2] = bb.z; wB[4*c4+3] = bb.w;
        }
    }
    float bi0 = b2[d0], bi1 = b2[d0+1];
    __syncthreads();   // lc ready
    float a1c = lc[dc], c1c = lc[64 + dc];
    float ls0 = 0.f, lq0 = 0.f, ls1 = 0.f, lq1 = 0.f;
    for (int e = 0; e < MCEN; e++) {
        int blk = blk0 + e;
        const float* zt = zbuf + (size_t)blk * 2048;
        float zv[8];
#pragma unroll
        for (int j = 0; j < 8; j++) zv[j] = zt[t + 256*j];
        if (e) __syncthreads();              // y1s reuse guard
#pragma unroll
        for (int j = 0; j < 8; j++) {
            float v = zv[j] * a1c + c1c;
            y1s[(t >> 6) + 4*j][dc] = v > 0.f ? v : 0.f;
        }
        __syncthreads();                     // y1s ready
        float acc0[8], acc1[8];
#pragma unroll
        for (int q = 0; q < 8; q++) { acc0[q] = bi0; acc1[q] = bi1; }
#pragma unroll
        for (int q = 0; q < 8; q++) {
            const float4* x4 = (const float4*)&y1s[sg*8 + q][0];
#pragma unroll
            for (int c4 = 0; c4 < 16; c4++) {
                float4 v = x4[c4];
                acc0[q] += v.x * wA[4*c4+0]; acc1[q] += v.x * wB[4*c4+0];
                acc0[q] += v.y * wA[4*c4+1]; acc1[q] += v.y * wB[4*c4+1];
                acc0[q] += v.z * wA[4*c4+2]; acc1[q] += v.z * wB[4*c4+2];
                acc0[q] += v.w * wA[4*c4+3]; acc1[q] += v.w * wB[4*c4+3];
            }
        }
        float* z2t = z2buf + (size_t)blk * 4096;
#pragma unroll
        for (int q = 0; q < 8; q++) {
            if (STOREZ) {
                int s = sg*8 + q;
                *(float2*)&z2t[s*128 + d0] = make_float2(acc0[q], acc1[q]);
            }
            ls0 += acc0[q]; lq0 += acc0[q]*acc0[q];
            ls1 += acc1[q]; lq1 += acc1[q]*acc1[q];
        }
    }
    rsum[d0][sg] = ls0; rsq[d0][sg] = lq0;
    rsum[d0+1][sg] = ls1; rsq[d0+1][sg] = lq1;
    __syncthreads();
    if (t < 128) {
        float s = 0.f, s2 = 0.f;
#pragma unroll
        for (int j = 0; j < 4; j++) { s += rsum[t][j]; s2 += rsq[t][j]; }
        float* sb = stats + (size_t)(blockIdx.x & (NBUCK-1)) * 512;
        atomicAdd(&sb[256 + t], s);
        atomicAdd(&sb[384 + t], s2);
    }
}

// S4z: z2 -> BN2+relu -> max -> out (streaming; used when z2 staged)
__global__ __launch_bounds__(256) void mlpS4z_kernel(
    const float* __restrict__ z2buf,
    const float* __restrict__ g2, const float* __restrict__ be2,
    const float* __restrict__ stats, float* __restrict__ out_feat) {
    __shared__ float red[256];
    __shared__ float lc[256];
    int blk = blockIdx.x, t = threadIdx.x;
    const float inv_n = 1.0f / (float)NTOT;
    if (t < 128) {
        float s = 0.f, s2 = 0.f;
        for (int j = 0; j < NBUCK; j++) { s += stats[j*512 + 256 + t]; s2 += stats[j*512 + 384 + t]; }
        float mean = s * inv_n, var = s2 * inv_n - mean * mean;
        float a = g2[t] * (1.0f / sqrtf(var + 1e-5f));
        lc[t] = a; lc[128 + t] = be2[t] - mean * a;
    }
    const float* z2t = z2buf + (size_t)blk * 4096;
    float zv[16];
#pragma unroll
    for (int j = 0; j < 16; j++) zv[j] = z2t[t + 256*j];
    __syncthreads();
    int d = t & 127;
    float a2 = lc[d], c2 = lc[128 + d];
    float lmax = -3.4e38f;
#pragma unroll
    for (int j = 0; j < 16; j++) {
        float v = zv[j] * a2 + c2;
        v = v > 0.f ? v : 0.f;
        lmax = v > lmax ? v : lmax;
    }
    red[t] = lmax;
    __syncthreads();
    if (t < 128) {
        float v = red[t] > red[t+128] ? red[t] : red[t+128];
        out_feat[(size_t)blk * C2 + t] = v;
    }
}

// S4r: recompute fallback (no z2 space): z1 -> BN1+relu -> L2 -> BN2+relu -> max
__global__ __launch_bounds__(256) void mlpS4r_kernel(
    const float* __restrict__ zbuf,
    const float* __restrict__ w2, const float* __restrict__ b2,
    const float* __restrict__ g1, const float* __restrict__ be1,
    const float* __restrict__ g2, const float* __restrict__ be2,
    const float* __restrict__ stats, float* __restrict__ out_feat) {
    __shared__ __align__(16) float y1s[S_][C1];
    __shared__ float rmax[128][5];
    __shared__ float lc[384];   // [a1 64|c1 64|a2 128|c2 128]
    int blk0 = blockIdx.x * MCEN, t = threadIdx.x;
    const float inv_n = 1.0f / (float)NTOT;
    if (t < 64) {
        float s = 0.f, s2 = 0.f;
        for (int j = 0; j < NBUCK; j++) { s += stats[j*512 + 128 + t]; s2 += stats[j*512 + 192 + t]; }
        float mean = s * inv_n, var = s2 * inv_n - mean * mean;
        float a = g1[t] * (1.0f / sqrtf(var + 1e-5f));
        lc[t] = a; lc[64 + t] = be1[t] - mean * a;
    }
    if (t < 128) {
        float s = 0.f, s2 = 0.f;
        for (int j = 0; j < NBUCK; j++) { s += stats[j*512 + 256 + t]; s2 += stats[j*512 + 384 + t]; }
        float mean = s * inv_n, var = s2 * inv_n - mean * mean;
        float a = g2[t] * (1.0f / sqrtf(var + 1e-5f));
        lc[128 + t] = a; lc[256 + t] = be2[t] - mean * a;
    }
    int dc = t & 63;
    int dp = t & 63, sg = t >> 6;
    int d0 = dp * 2;
    float wA[64], wB[64];
    {
        const float4* wa4 = (const float4*)(w2 + (size_t)d0 * C1);
        const float4* wb4 = (const float4*)(w2 + (size_t)(d0+1) * C1);
#pragma unroll
        for (int c4 = 0; c4 < 16; c4++) {
            float4 a = wa4[c4], bb = wb4[c4];
            wA[4*c4+0] = a.x;  wA[4*c4+1] = a.y;  wA[4*c4+2] = a.z;  wA[4*c4+3] = a.w;
            wB[4*c4+0] = bb.x; wB[4*c4+1] = bb.y; wB[4*c4+2] = bb.z; wB[4*c4+3] = bb.w;
        }
    }
    float bi0 = b2[d0], bi1 = b2[d0+1];
    __syncthreads();   // lc ready
    float a1c = lc[dc], c1c = lc[64 + dc];
    float a20 = lc[128 + d0], c20 = lc[256 + d0];
    float a21 = lc[128 + d0 + 1], c21 = lc[256 + d0 + 1];
    for (int e = 0; e < MCEN; e++) {
        int blk = blk0 + e;
        const float* zt = zbuf + (size_t)blk * 2048;
        float zv[8];
#pragma unroll
        for (int j = 0; j < 8; j++) zv[j] = zt[t + 256*j];
        if (e) __syncthreads();              // y1s/rmax reuse guard
#pragma unroll
        for (int j = 0; j < 8; j++) {
            float v = zv[j] * a1c + c1c;
            y1s[(t >> 6) + 4*j][dc] = v > 0.f ? v : 0.f;
        }
        __syncthreads();                     // y1s ready
        float acc0[8], acc1[8];
#pragma unroll
        for (int q = 0; q < 8; q++) { acc0[q] = bi0; acc1[q] = bi1; }
#pragma unroll
        for (int q = 0; q < 8; q++) {
            const float4* x4 = (const float4*)&y1s[sg*8 + q][0];
#pragma unroll
            for (int c4 = 0; c4 < 16; c4++) {
                float4 v = x4[c4];
                acc0[q] += v.x * wA[4*c4+0]; acc1[q] += v.x * wB[4*c4+0];
                acc0[q] += v.y * wA[4*c4+1]; acc1[q] += v.y * wB[4*c4+1];
                acc0[q] += v.z * wA[4*c4+2]; acc1[q] += v.z * wB[4*c4+2];
                acc0[q] += v.w * wA[4*c4+3]; acc1[q] += v.w * wB[4*c4+3];
            }
        }
        float lm0 = -3.4e38f, lm1 = -3.4e38f;
#pragma unroll
        for (int q = 0; q < 8; q++) {
            float v0 = acc0[q] * a20 + c20; v0 = v0 > 0.f ? v0 : 0.f;
            float v1 = acc1[q] * a21 + c21; v1 = v1 > 0.f ? v1 : 0.f;
            lm0 = v0 > lm0 ? v0 : lm0;
            lm1 = v1 > lm1 ? v1 : lm1;
        }
        rmax[d0][sg] = lm0; rmax[d0+1][sg] = lm1;
        __syncthreads();                     // rmax ready
        if (t < 128) {
            float v = rmax[t][0];
#pragma unroll
            for (int j = 1; j < 4; j++) v = rmax[t][j] > v ? rmax[t][j] : v;
            out_feat[(size_t)blk * C2 + t] = v;
        }
    }
}

extern "C" void kernel_launch(void* const* d_in, const int* in_sizes, int n_in,
                              void* d_out, int out_size, void* d_ws, size_t ws_size,
                              hipStream_t stream) {
    const float* xyz  = (const float*)d_in[0];
    const float* feat = (const float*)d_in[1];
    const float* w0 = (const float*)d_in[2];  const float* b0 = (const float*)d_in[3];
    const float* g0 = (const float*)d_in[4];  const float* be0 = (const float*)d_in[5];
    const float* w1 = (const float*)d_in[6];  const float* b1 = (const float*)d_in[7];
    const float* g1 = (const float*)d_in[8];  const float* be1 = (const float*)d_in[9];
    const float* w2 = (const float*)d_in[10]; const float* b2 = (const float*)d_in[11];
    const float* g2 = (const float*)d_in[12]; const float* be2 = (const float*)d_in[13];
    float* out_xyz  = (float*)d_out;
    float* out_feat = out_xyz + B_*M_*3;

    int* fps_i  = (int*)d_ws;                                   // 64 KB
    int* ball_i = (int*)((char*)d_ws + 65536);                  // 2 MB
    float* stats = (float*)((char*)d_ws + 65536 + 2097152);     // 32 KB
    size_t zoff = 65536 + 2097152 + (size_t)NBUCK*512*4;
    float* zbuf = (float*)((char*)d_ws + zoff);                 // 128 MB (proven fits)
    float* z2buf = zbuf + (size_t)B_*M_ * 2048;                 // +256 MB (guarded)
    size_t need2 = zoff + (size_t)B_*M_ * 2048 * 4 + (size_t)B_*M_ * 4096 * 4;
    bool stage_z2 = ws_size >= need2;

    hipMemsetAsync(stats, 0, NBUCK*512*sizeof(float), stream);
    fps_kernel<<<B_, FPS_T, 0, stream>>>(xyz, fps_i, out_xyz);
    ballq_kernel<<<B_ * (M_/BQ_G), 256, 0, stream>>>(xyz, fps_i, ball_i);
    mlpS1_kernel<<<(B_*M_)/MCEN, 256, 0, stream>>>(xyz, feat, fps_i, ball_i, w0, b0, zbuf, stats);
    mlpS2_kernel<<<(B_*M_)/MCEN, 256, 0, stream>>>(zbuf, w1, b1, g0, be0, stats);
    if (stage_z2) {
        mlpS3_kernel<1><<<(B_*M_)/MCEN, 256, 0, stream>>>(zbuf, w2, b2, g1, be1, z2buf, stats);
        mlpS4z_kernel<<<B_*M_, 256, 0, stream>>>(z2buf, g2, be2, stats, out_feat);
    } else {
        mlpS3_kernel<0><<<(B_*M_)/MCEN, 256, 0, stream>>>(zbuf, w2, b2, g1, be1, z2buf, stats);
        mlpS4r_kernel<<<(B_*M_)/MCEN, 256, 0, stream>>>(zbuf, w2, b2, g1, be1, g2, be2, stats, out_feat);
    }
}